// Round 9
// baseline (124.586 us; speedup 1.0000x reference)
//
#include <hip/hip_runtime.h>

#define HW 256
#define CH 64
#define NPIX (4 * HW * HW)              // 262144 pixels
#define ENC_BYTES ((size_t)NPIX * 24)   // 12 u16 per pixel (9 used)
#define DM_OFF ((size_t)8 << 20)        // dm region at ws+8MB
#define DM_BYTES ((size_t)NPIX * 48)    // 12 f32 per pixel (9 used)
#define WS_NEED (DM_OFF + DM_BYTES)

// ===================== Kernel A: address precompute (verified r2/r3/r5/r6/r8) =====================
// One thread per (pixel, tap): enc = (y0<<8)|x0 u16. 36k waves -> latency-free.
__global__ __launch_bounds__(256, 8) void DeformA_kernel(
    const float* __restrict__ gt,     // [256,256]
    const float* __restrict__ off,    // [4,256,256,18]
    unsigned short* __restrict__ enc) // [NPIX][12]
{
    const unsigned g = blockIdx.x * 256u + threadIdx.x;   // < NPIX*9
    const unsigned p = g / 9u;                             // magic-mul
    const int tap = (int)(g - p * 9u);
    const int i = (int)((p >> 8) & 255u);
    const int j = (int)(p & 255u);
    const int ky = tap / 3, kx = tap - ky * 3;

    const float2 o2 = *(const float2*)(off + (size_t)g * 2);

    const int iy = i + ky - 1, ix = j + kx - 1;
    const bool interior = (iy >= 0) & (iy < HW) & (ix >= 0) & (ix < HW);
    const int yi = interior ? iy : 0;
    const int xi = interior ? ix : 0;
    const float p_mask = (yi >= 1 && xi >= 1) ? gt[(yi - 1) * HW + (xi - 1)] : 0.f;

    const float yf = (float)yi, xf = (float)xi;
    const float yof = fminf(fmaxf(floorf(yf + o2.x), 0.f), 257.f);
    const float xof = fminf(fmaxf(floorf(xf + o2.y), 0.f), 257.f);
    const int yo = (int)yof, xo = (int)xof;
    const float p_mask_off = (yo >= 1 && yo <= HW && xo >= 1 && xo <= HW)
                             ? gt[(yo - 1) * HW + (xo - 1)] : 0.f;
    const float diff = (p_mask != p_mask_off) ? 1.f : 0.f;
    const float y = fminf(fmaxf(yf + o2.x * diff, 0.f), 255.f);
    const float x = fminf(fmaxf(xf + o2.y * diff, 0.f), 255.f);
    const int y0 = (int)y, x0 = (int)x;   // in [0,255]; valid iff >=1

    enc[p * 12u + (unsigned)tap] = (unsigned short)((y0 << 8) | x0);
}

// ---- DPP rotate-add (verified r8): x + ror16(x,N). VALU pipe, no DS. ----
template <int CTRL>
__device__ __forceinline__ float dpp_ror_add(float x) {
    int xi = __builtin_bit_cast(int, x);
    int yi = __builtin_amdgcn_update_dpp(0, xi, CTRL, 0xF, 0xF, false);
    return x + __builtin_bit_cast(float, yi);
}
#define ROR1 0x121
#define ROR2 0x122
#define ROR4 0x124
#define ROR8 0x128

// ===================== Kernel D4: barrier-free, reg-weight, full-line stores ====
// dm[p][k] = sum_c inp[p][c]*ker[k][c].
// Round-8 lesson: D3 ~27us vs 12us pipe floor. Three layout artifacts:
// (1) per-block ker-stage + __syncthreads exposed ~5us of barrier wait;
// (2) 9x4B stores left every 64B line partially written (RMW traffic);
// (3) v0/v1 strided 4x256B per wave-instr.
// D4: weights in 36 VGPRs per thread (L2-hot ker, loaded once, NO LDS/
// barrier); group g -> pixel base+g so loads are flat 1KB bursts; stores
// write all 12 slots (9 sums + 3 zeros) -> 384B fully-covered lines per
// wave-iter (C2 never reads slots 9..11). 4 iters/wave, unroll-4 lets
// next-iter loads pipeline under the DPP reduce. bounds(256,4): ~90 VGPR.
__global__ __launch_bounds__(256, 4) void DeformD4_kernel(
    const float* __restrict__ inp,    // [NPIX][64]
    const float* __restrict__ ker,    // [9][64]
    float* __restrict__ dm)           // [NPIX][12]
{
    const int lane = threadIdx.x & 63;
    const int wave = threadIdx.x >> 6;
    const int t = lane & 15;          // channel quad
    const int g = lane >> 4;          // pixel-in-group

    float4 wk[9];
    #pragma unroll
    for (int k = 0; k < 9; ++k)
        wk[k] = *(const float4*)(ker + k * 64 + t * 4);

    // block covers 128 px; wave covers 32: 4 iters x 8 px
    const int pxbase = blockIdx.x * 128 + wave * 32;

    #pragma unroll
    for (int it = 0; it < 4; ++it) {
        const int pA = pxbase + it * 8 + g;     // px 0..3  (v0: flat 1KB/wave)
        const int pB = pA + 4;                  // px 4..7  (v1: flat 1KB/wave)
        const float4 v0 = *(const float4*)(inp + (size_t)pA * 64 + t * 4);
        const float4 v1 = *(const float4*)(inp + (size_t)pB * 64 + t * 4);

        float da[9], db[9];
        #pragma unroll
        for (int k = 0; k < 9; ++k) {
            const float4 w = wk[k];
            da[k] = v0.x * w.x + v0.y * w.y + v0.z * w.z + v0.w * w.w;
            db[k] = v1.x * w.x + v1.y * w.y + v1.z * w.z + v1.w * w.w;
        }
        #pragma unroll
        for (int k = 0; k < 9; ++k) {
            da[k] = dpp_ror_add<ROR8>(da[k]);
            da[k] = dpp_ror_add<ROR4>(da[k]);
            da[k] = dpp_ror_add<ROR2>(da[k]);
            da[k] = dpp_ror_add<ROR1>(da[k]);
            db[k] = dpp_ror_add<ROR8>(db[k]);
            db[k] = dpp_ror_add<ROR4>(db[k]);
            db[k] = dpp_ror_add<ROR2>(db[k]);
            db[k] = dpp_ror_add<ROR1>(db[k]);
        }
        // every lane holds all 9 sums; lane t stores slot t (zeros for 9..11)
        float sa = 0.f, sb = 0.f;
        #pragma unroll
        for (int k = 8; k >= 0; --k) {
            sa = (t == k) ? da[k] : sa;
            sb = (t == k) ? db[k] : sb;
        }
        if (t < 12) {
            dm[(size_t)pA * 12 + t] = sa;       // 12 lanes x 4B x 4 groups
            dm[(size_t)pB * 12 + t] = sb;       //   = 192B contiguous each
        }
    }
}

// ===================== Kernel C2: gather precomputed dots (verified r5/r6/r8) =====================
__global__ __launch_bounds__(256, 8) void DeformC2_kernel(
    const unsigned short* __restrict__ enc,  // [NPIX][12]
    const float* __restrict__ dm,            // [NPIX][12]
    const float* __restrict__ bias,
    float* __restrict__ out)                 // [NPIX]
{
    const int tid = threadIdx.x;
    const int bid = blockIdx.x;
    const int vb = (bid & 7) * 128 + (bid >> 3);   // XCD swizzle, 1024 blocks
    const int p = vb * 256 + tid;
    const int b = p >> 16;
    const float* dmb = dm + (size_t)(b << 16) * 12;

    const uint2* e = (const uint2*)(enc + (size_t)p * 12u);
    const uint2 eA = e[0];                         // taps 0..3
    const uint2 eB = e[1];                         // taps 4..7
    const unsigned eC = *(const unsigned*)(e + 2); // tap 8

    unsigned en[9];
    en[0] = eA.x & 0xffffu; en[1] = eA.x >> 16;
    en[2] = eA.y & 0xffffu; en[3] = eA.y >> 16;
    en[4] = eB.x & 0xffffu; en[5] = eB.x >> 16;
    en[6] = eB.y & 0xffffu; en[7] = eB.y >> 16;
    en[8] = eC & 0xffffu;

    float v[9];
    int msk = 0;
    #pragma unroll
    for (int k = 0; k < 9; ++k) {
        const int yy = (int)(en[k] >> 8);
        const int xx = (int)(en[k] & 255u);
        const bool valid = (yy >= 1) & (xx >= 1);
        msk |= (int)valid << k;
        const int idx = valid ? ((yy - 1) * HW + (xx - 1)) : 0;
        v[k] = dmb[(size_t)idx * 12 + k];
    }
    float sum = 0.f;
    #pragma unroll
    for (int k = 0; k < 9; ++k)
        sum += ((msk >> k) & 1) ? v[k] : 0.f;

    out[p] = sum + bias[0];
}

// ===================== Fallback (round-0 verified kernel) =====================
__global__ __launch_bounds__(256, 6) void DeformFallback_kernel(
    const float* __restrict__ inp, const float* __restrict__ gt,
    const float* __restrict__ off, const float* __restrict__ ker,
    const float* __restrict__ bias, float* __restrict__ out)
{
    __shared__ float wlds[576];
    const int tid = threadIdx.x;
    if (tid < 144) ((float4*)wlds)[tid] = ((const float4*)ker)[tid];

    const int lane = tid & 63;
    const int wave = tid >> 6;
    const int q16  = lane & 48;
    const int t    = lane & 15;

    const int bid = blockIdx.x;
    const int vb  = (bid & 7) * 2048 + (bid >> 3);

    const int p = vb * 16 + wave * 4 + (q16 >> 4);
    const int b = p >> 16;
    const int i = (p >> 8) & 255;
    const int j = p & 255;
    const float* inb = inp + (long)b * (HW * HW * CH);

    int pack = 0;
    if (t < 9) {
        const int tap = t;
        const int ky = tap / 3, kx = tap - ky * 3;
        int iy = i + ky - 1, ix = j + kx - 1;
        bool interior = (iy >= 0) & (iy < HW) & (ix >= 0) & (ix < HW);
        int yi = interior ? iy : 0;
        int xi = interior ? ix : 0;
        float p_mask = (yi >= 1 && xi >= 1) ? gt[(yi - 1) * HW + (xi - 1)] : 0.f;
        float2 o2 = *(const float2*)(off + (long)p * 18 + 2 * tap);
        float yf = (float)yi, xf = (float)xi;
        float yof = fminf(fmaxf(floorf(yf + o2.x), 0.f), 257.f);
        float xof = fminf(fmaxf(floorf(xf + o2.y), 0.f), 257.f);
        int yo = (int)yof, xo = (int)xof;
        float p_mask_off = (yo >= 1 && yo <= HW && xo >= 1 && xo <= HW)
                           ? gt[(yo - 1) * HW + (xo - 1)] : 0.f;
        float diff = (p_mask != p_mask_off) ? 1.f : 0.f;
        float y = fminf(fmaxf(yf + o2.x * diff, 0.f), 255.f);
        float x = fminf(fmaxf(xf + o2.y * diff, 0.f), 255.f);
        int y0 = (int)y;
        int x0 = (int)x;
        bool valid = (y0 >= 1) & (x0 >= 1);
        int eoff = ((y0 - 1) * HW + (x0 - 1)) * CH;
        pack = valid ? eoff : -1;
    }

    int pk[9];
    #pragma unroll
    for (int k = 0; k < 9; ++k) pk[k] = __shfl(pack, q16 + k);

    float4 v[9];
    #pragma unroll
    for (int k = 0; k < 9; ++k) {
        int eo2 = pk[k] >= 0 ? pk[k] : 0;
        v[k] = *(const float4*)(inb + eo2 + t * 4);
    }

    __syncthreads();

    float acc = 0.f;
    #pragma unroll
    for (int k = 0; k < 9; ++k) {
        float s = pk[k] >= 0 ? 1.f : 0.f;
        float4 w = ((const float4*)wlds)[k * 16 + t];
        float d = v[k].x * w.x + v[k].y * w.y + v[k].z * w.z + v[k].w * w.w;
        acc = fmaf(s, d, acc);
    }

    acc += __shfl_xor(acc, 8);
    acc += __shfl_xor(acc, 4);
    acc += __shfl_xor(acc, 2);
    acc += __shfl_xor(acc, 1);
    if (t == 0) out[p] = acc + bias[0];
}

extern "C" void kernel_launch(void* const* d_in, const int* in_sizes, int n_in,
                              void* d_out, int out_size, void* d_ws, size_t ws_size,
                              hipStream_t stream) {
    const float* inp  = (const float*)d_in[0];
    const float* gt   = (const float*)d_in[1];
    const float* off  = (const float*)d_in[2];
    const float* ker  = (const float*)d_in[3];
    const float* bias = (const float*)d_in[4];
    float* out = (float*)d_out;

    if (d_ws != nullptr && ws_size >= WS_NEED) {
        unsigned short* enc = (unsigned short*)d_ws;
        float* dm = (float*)((char*)d_ws + DM_OFF);
        // A: 262144*9 / 256 = 9216 blocks ; D4: 262144/128 = 2048 ; C2: 1024
        DeformA_kernel<<<9216, 256, 0, stream>>>(gt, off, enc);
        DeformD4_kernel<<<2048, 256, 0, stream>>>(inp, ker, dm);
        DeformC2_kernel<<<1024, 256, 0, stream>>>(enc, dm, bias, out);
    } else {
        DeformFallback_kernel<<<16384, 256, 0, stream>>>(inp, gt, off, ker, bias, out);
    }
}